// Round 4
// baseline (144.640 us; speedup 1.0000x reference)
//
#include <hip/hip_runtime.h>

// Problem constants: B=2, C=32, H=128, W=256, maxdisp=12 -> D=23, shift = di-11
#define BB 2
#define CC 32
#define HH 128
#define WW 256
#define DD 23
#define HW (HH * WW)

#define SEG 64            // pixels per block (W split 4 ways)
#define NSEG 4
#define NCOLS 151         // staged cols: [64s-75 .. 64s+75]
#define SC 36             // col stride in dwords (144 B, 16B-aligned)

// LDS: smem[col*SC + c] = feat_r[b, c, h, col + COL0], zero outside [0,W).
// After compute it is reused as the partial-sum slab: slab[(di*3+j)*64+px],
// j = rank of non-owner wave (3*23*64*4 B = 17664 <= 21744).

__global__ __launch_bounds__(256, 4) void cost_volume_kernel(
    const float* __restrict__ feat_l,
    const float* __restrict__ feat_r,
    const float* __restrict__ disp,
    float* __restrict__ out)
{
    __shared__ __align__(16) float smem[NCOLS * SC];   // 21744 B

    const int t  = threadIdx.x;
    const int q  = t >> 6;          // wave id = channel octet (c0 = 8q)
    const int px = t & 63;          // pixel within segment
    const int s  = blockIdx.x >> 8; // grid = NSEG*256; siblings same XCD
    const int bh = blockIdx.x & 255;
    const int b  = bh >> 7;
    const int h  = bh & 127;
    const int w  = s * SEG + px;
    const int COL0 = s * SEG - 75;
    const int c0 = q * 8;

    // ---- stage feat_r window FIRST (starts LDS-fill critical path early) ----
    #pragma unroll
    for (int cc = 0; cc < 3; ++cc) {
        const int col = cc * 64 + px;
        if (col < NCOLS) {
            const int  gcol = col + COL0;
            const bool inr  = (gcol >= 0) && (gcol < WW);
            const int  gc   = min(max(gcol, 0), WW - 1);   // safe address
            #pragma unroll
            for (int qq = 0; qq < 2; ++qq) {
                const int cq = (q + 4 * qq) * 4;           // channel quad base
                const size_t base = ((size_t)(b * CC + cq)) * HW + (size_t)h * WW + gc;
                const float x0 = feat_r[base];
                const float x1 = feat_r[base + HW];
                const float x2 = feat_r[base + 2 * HW];
                const float x3 = feat_r[base + 3 * HW];
                float4 v;
                v.x = inr ? x0 : 0.0f;
                v.y = inr ? x1 : 0.0f;
                v.z = inr ? x2 : 0.0f;
                v.w = inr ? x3 : 0.0f;
                *(float4*)&smem[col * SC + cq] = v;
            }
        }
    }

    // ---- single-use global loads: nontemporal (don't pollute L2) ----
    float fl[8];
    const size_t lbase = ((size_t)(b * CC + c0)) * HW + (size_t)h * WW + w;
    #pragma unroll
    for (int k = 0; k < 8; ++k)
        fl[k] = __builtin_nontemporal_load(&feat_l[lbase + (size_t)k * HW]);
    const float d = disp[(size_t)bh * WW + w];

    __syncthreads();

    // ---- per-pixel interp setup (shared across all di) ----
    const float pxf = (float)w - d;
    const float x0f = floorf(pxf);
    const float w1  = pxf - x0f;          // right-neighbor weight
    const float w0  = 1.0f - w1;
    int lb = (int)x0f - COL0 - 11;        // local col of tap j=0
    lb = min(max(lb, 0), NCOLS - 24);     // no-op for disp in [0,64)

    // ---- 24-tap window, prefetch distance 2, 8 channels per thread ----
    float4 Ta[3], Tb[3];
    #define LOADTAP(idx, j) { \
        const float4* p_ = (const float4*)&smem[(lb + (j)) * SC + c0]; \
        Ta[idx] = p_[0]; Tb[idx] = p_[1]; }

    LOADTAP(0, 0)
    LOADTAP(1, 1)

    float acc[DD];
    #pragma unroll
    for (int di = 0; di < DD; ++di) {
        if (di + 2 < 24) LOADTAP((di + 2) % 3, di + 2)
        const float4 A0 = Ta[di % 3],       A1 = Tb[di % 3];
        const float4 B0 = Ta[(di + 1) % 3], B1 = Tb[(di + 1) % 3];
        float sA = 0.0f, sB = 0.0f;
        sA += fabsf(fmaf(w0, A0.x, fmaf(w1, B0.x, -fl[0])));
        sB += fabsf(fmaf(w0, A0.y, fmaf(w1, B0.y, -fl[1])));
        sA += fabsf(fmaf(w0, A0.z, fmaf(w1, B0.z, -fl[2])));
        sB += fabsf(fmaf(w0, A0.w, fmaf(w1, B0.w, -fl[3])));
        sA += fabsf(fmaf(w0, A1.x, fmaf(w1, B1.x, -fl[4])));
        sB += fabsf(fmaf(w0, A1.y, fmaf(w1, B1.y, -fl[5])));
        sA += fabsf(fmaf(w0, A1.z, fmaf(w1, B1.z, -fl[6])));
        sB += fabsf(fmaf(w0, A1.w, fmaf(w1, B1.w, -fl[7])));
        acc[di] = sA + sB;
    }
    #undef LOADTAP

    // ---- balanced 4-way combine: wave q owns di in [6q, 6q+6) (last: 5) ----
    __syncthreads();                      // all tap reads done before overwrite
    #pragma unroll
    for (int di = 0; di < DD; ++di) {
        const int own = (di < 6) ? 0 : (di < 12) ? 1 : (di < 18) ? 2 : 3;
        if (own != q) {
            const int j = q - (q > own ? 1 : 0);          // 0..2
            smem[(di * 3 + j) * 64 + px] = acc[di];       // stride-1: no conflicts
        }
    }
    __syncthreads();
    {
        const int d0 = q * 6;
        #pragma unroll
        for (int k = 0; k < 6; ++k) {
            const int di = d0 + k;
            if (di < DD) {
                const float v = acc[di]
                              + smem[(di * 3 + 0) * 64 + px]
                              + smem[(di * 3 + 1) * 64 + px]
                              + smem[(di * 3 + 2) * 64 + px];
                __builtin_nontemporal_store(
                    v, &out[((size_t)(b * DD + di)) * HW + (size_t)h * WW + w]);
            }
        }
    }
}

extern "C" void kernel_launch(void* const* d_in, const int* in_sizes, int n_in,
                              void* d_out, int out_size, void* d_ws, size_t ws_size,
                              hipStream_t stream)
{
    const float* feat_l = (const float*)d_in[0];
    const float* feat_r = (const float*)d_in[1];
    const float* disp   = (const float*)d_in[2];
    float* out = (float*)d_out;

    dim3 grid(NSEG * BB * HH);   // 1024 blocks: (wseg, b, h); 4 blocks/CU
    dim3 block(256);             // 4 waves: one channel-octet each
    cost_volume_kernel<<<grid, block, 0, stream>>>(feat_l, feat_r, disp, out);
}